// Round 2
// baseline (503.699 us; speedup 1.0000x reference)
//
#include <hip/hip_runtime.h>

#define N_IMG 32
#define C_IN  256
#define C_OUT 32
#define HWDIM 56
#define C_TOT 288
#define EPSV  1e-5f
#define PLANE (HWDIM * HWDIM)      // 3136
#define CHW   (C_TOT * PLANE)      // 903168

// One block per (h, n). Block = 256 threads = 32 oc-groups x 8 w-groups.
// LDS: y tile for rows h-1..h+1, 32 channels per chunk, w entries 0..57
// (entry e corresponds to input column e-1; e=0 and e=57 are zero halo).
__global__ __launch_bounds__(256) void fused_bn_relu_conv(
    const float* __restrict__ xin,
    const float* __restrict__ bnw,
    const float* __restrict__ bnb,
    const float* __restrict__ rmean,
    const float* __restrict__ rvar,
    const float* __restrict__ cw,
    float* __restrict__ out)
{
    __shared__ float s_scale[C_IN];
    __shared__ float s_shift[C_IN];
    __shared__ float s_y[3][32][60];   // [row][ic][w_eff], stride 60 floats

    const int h = blockIdx.x;
    const int n = blockIdx.y;
    const int t = threadIdx.x;

    // Per-channel BN affine: scale = gamma * rsqrt(var+eps), shift = beta - mean*scale
    {
        float v  = rvar[t];
        float sc = bnw[t] * rsqrtf(v + EPSV);
        s_scale[t] = sc;
        s_shift[t] = bnb[t] - rmean[t] * sc;
    }

    const int oc = t >> 3;          // 0..31
    const int w0 = (t & 7) * 7;     // 0,7,...,49  -> 7 outputs per thread

    float acc[7];
    #pragma unroll
    for (int j = 0; j < 7; ++j) acc[j] = 0.f;

    const size_t nbase = (size_t)n * CHW;

    for (int cb = 0; cb < 8; ++cb) {
        __syncthreads();   // previous chunk's readers done (also covers scale staging on cb==0)

        // ---- stage y = relu(scale*x + shift) for 3 rows x 32 ic x 56 w ----
        // tasks: (r, ic, s): s<14 -> one float4 of the row; s==14 -> zero halo
        for (int idx = t; idx < 3 * 32 * 15; idx += 256) {
            int r   = idx / 480;
            int rem = idx - r * 480;
            int ic  = rem / 15;
            int s   = rem - ic * 15;
            int icg = (cb << 5) + ic;
            int hr  = h - 1 + r;
            if (s < 14) {
                float4 x = make_float4(0.f, 0.f, 0.f, 0.f);
                if ((unsigned)hr < HWDIM) {
                    const float* gp = xin + nbase + (size_t)icg * PLANE + hr * HWDIM + (s << 2);
                    x = *reinterpret_cast<const float4*>(gp);
                    if (r == 1) {
                        // fused pass-through: original x of the middle row -> output ch 0..255
                        float* op = out + nbase + (size_t)icg * PLANE + h * HWDIM + (s << 2);
                        *reinterpret_cast<float4*>(op) = x;
                    }
                }
                float sc = s_scale[icg], sh = s_shift[icg];
                int e = (s << 2) + 1;
                s_y[r][ic][e + 0] = fmaxf(fmaf(x.x, sc, sh), 0.f);
                s_y[r][ic][e + 1] = fmaxf(fmaf(x.y, sc, sh), 0.f);
                s_y[r][ic][e + 2] = fmaxf(fmaf(x.z, sc, sh), 0.f);
                s_y[r][ic][e + 3] = fmaxf(fmaf(x.w, sc, sh), 0.f);
            } else {
                s_y[r][ic][0]  = 0.f;   // column -1 halo
                s_y[r][ic][57] = 0.f;   // column 56 halo
            }
        }
        __syncthreads();

        // ---- accumulate 32 input channels ----
        const float* wbase = cw + ((size_t)oc * C_IN + (cb << 5)) * 9;
        #pragma unroll 2
        for (int ic = 0; ic < 32; ++ic) {
            const float* wp = wbase + ic * 9;
            float wk[9];
            #pragma unroll
            for (int k = 0; k < 9; ++k) wk[k] = wp[k];   // broadcast across 8 lanes/oc
            #pragma unroll
            for (int r = 0; r < 3; ++r) {
                float yy[9];
                #pragma unroll
                for (int j = 0; j < 9; ++j) yy[j] = s_y[r][ic][w0 + j];
                #pragma unroll
                for (int kw = 0; kw < 3; ++kw) {
                    float wv = wk[r * 3 + kw];
                    #pragma unroll
                    for (int j = 0; j < 7; ++j)
                        acc[j] = fmaf(yy[j + kw], wv, acc[j]);
                }
            }
        }
    }

    // ---- write conv result: output channels 256..287 ----
    float* op = out + nbase + (size_t)(C_IN + oc) * PLANE + h * HWDIM + w0;
    #pragma unroll
    for (int j = 0; j < 7; ++j) op[j] = acc[j];
}

extern "C" void kernel_launch(void* const* d_in, const int* in_sizes, int n_in,
                              void* d_out, int out_size, void* d_ws, size_t ws_size,
                              hipStream_t stream) {
    const float* xin  = (const float*)d_in[0];
    const float* bnw  = (const float*)d_in[1];
    const float* bnb  = (const float*)d_in[2];
    const float* rm   = (const float*)d_in[3];
    const float* rv   = (const float*)d_in[4];
    const float* cwt  = (const float*)d_in[5];
    float* out = (float*)d_out;

    dim3 grid(HWDIM, N_IMG);   // (h, n)
    fused_bn_relu_conv<<<grid, 256, 0, stream>>>(xin, bnw, bnb, rm, rv, cwt, out);
}

// Round 3
// 329.830 us; speedup vs baseline: 1.5271x; 1.5271x over previous
//
#include <hip/hip_runtime.h>

typedef short short8 __attribute__((ext_vector_type(8)));
typedef float f32x4 __attribute__((ext_vector_type(4)));

#define N_IMG 32
#define C_IN  256
#define C_OUT 32
#define HWDIM 56
#define C_TOT 288
#define EPSV  1e-5f
#define PLANE (HWDIM * HWDIM)      // 3136
#define CHW   (C_TOT * PLANE)      // 903168

// padded bf16 NHWC y workspace: [n][58][58][256]
#define YP    58
#define YROW  (YP * C_IN)          // 14848 elems per padded row
#define YIMG  (YP * YROW)          // 861184 elems per image
#define YWS_ELEMS ((size_t)N_IMG * YIMG)
#define WT_ELEMS  (9 * C_OUT * C_IN)          // 73728
#define WS_NEED   (YWS_ELEMS * 2 + (size_t)WT_ELEMS * 2)

static __device__ __forceinline__ unsigned short f2bf(float f) {
    union { float f; unsigned u; } v; v.f = f;
    unsigned r = (v.u + 0x7FFFu + ((v.u >> 16) & 1u)) >> 16;   // RNE
    return (unsigned short)r;
}

// ---------------------------------------------------------------------------
// prep: (a) zero padded borders of yws  (b) convert conv weights to bf16
//        wt layout: [tap(kh*3+kw)][oc][ic], ic contiguous
// ---------------------------------------------------------------------------
__global__ __launch_bounds__(256) void prep_kernel(const float* __restrict__ cw,
                                                   unsigned short* __restrict__ yws,
                                                   unsigned short* __restrict__ wt) {
    int b = blockIdx.x, t = threadIdx.x;
    if (b < 912) {
        int gid = b * 256 + t;            // 0..233471 ; 32 img * 228 border px * 32 chunks
        int px = gid >> 5, ch = gid & 31;
        int n = px / 228, r = px % 228;
        int hh, ww;
        if (r < 58)       { hh = 0;        ww = r;       }
        else if (r < 116) { hh = 57;       ww = r - 58;  }
        else if (r < 172) { hh = r - 115;  ww = 0;       }   // h' = 1..56
        else              { hh = r - 171;  ww = 57;      }
        uint4 z = {0u, 0u, 0u, 0u};
        *(uint4*)((char*)yws + ((size_t)n * YIMG + (size_t)hh * YROW + (size_t)ww * C_IN) * 2 + ch * 16) = z;
    } else {
        int id  = (b - 912) * 256 + t;    // 0..73727
        int tap = id >> 13;               // /8192
        int oc  = (id >> 8) & 31;
        int ic  = id & 255;
        wt[id] = f2bf(cw[(oc * C_IN + ic) * 9 + tap]);
    }
}

// ---------------------------------------------------------------------------
// k1: passthrough copy (fp32 NCHW) + BN+ReLU -> bf16 NHWC-padded workspace.
// One block per (h, n). LDS transpose [w][c].
// ---------------------------------------------------------------------------
__global__ __launch_bounds__(256) void bn_relu_pack(const float* __restrict__ xin,
                                                    const float* __restrict__ bnw,
                                                    const float* __restrict__ bnb,
                                                    const float* __restrict__ rmean,
                                                    const float* __restrict__ rvar,
                                                    float* __restrict__ out,
                                                    unsigned short* __restrict__ yws) {
    __shared__ float s_scale[C_IN], s_shift[C_IN];
    __shared__ unsigned short s_y[HWDIM * 264 + 8];   // [w][c] stride 264

    int h = blockIdx.x, n = blockIdx.y, t = threadIdx.x;
    {
        float sc = bnw[t] * rsqrtf(rvar[t] + EPSV);
        s_scale[t] = sc;
        s_shift[t] = bnb[t] - rmean[t] * sc;
    }
    __syncthreads();

    const size_t nb = (size_t)n * CHW + (size_t)h * HWDIM;
    #pragma unroll
    for (int i = 0; i < 14; ++i) {
        int id = i * 256 + t;             // 3584 tasks = 256 c * 14 w-quads
        int c = id / 14, wq = id - c * 14;
        const float* gp = xin + nb + (size_t)c * PLANE + wq * 4;
        float4 x = *(const float4*)gp;
        *(float4*)(out + nb + (size_t)c * PLANE + wq * 4) = x;   // fused passthrough
        float sc = s_scale[c], sh = s_shift[c];
        int wb = wq * 4;
        s_y[(wb + 0) * 264 + c] = f2bf(fmaxf(fmaf(x.x, sc, sh), 0.f));
        s_y[(wb + 1) * 264 + c] = f2bf(fmaxf(fmaf(x.y, sc, sh), 0.f));
        s_y[(wb + 2) * 264 + c] = f2bf(fmaxf(fmaf(x.z, sc, sh), 0.f));
        s_y[(wb + 3) * 264 + c] = f2bf(fmaxf(fmaf(x.w, sc, sh), 0.f));
    }
    __syncthreads();

    unsigned short* ybase = yws + (size_t)n * YIMG + (size_t)(h + 1) * YROW + C_IN; // col 1
    #pragma unroll
    for (int i = 0; i < 7; ++i) {
        int id = i * 256 + t;             // 1792 16B-chunks = 56 px * 32
        int px = id >> 5, co = (id & 31) * 8;
        uint4 v = *(uint4*)((char*)s_y + ((size_t)px * 264 + co) * 2);
        *(uint4*)((char*)ybase + ((size_t)px * C_IN + co) * 2) = v;
    }
}

// ---------------------------------------------------------------------------
// k2: implicit-GEMM conv via MFMA. Block = 256 thr (4 waves), 2 output rows
// (112 px = 7 M-tiles of 16; wave w owns tiles 2w,2w+1, wave 3 has 1).
// A = weights (LDS, XOR-swizzled), B = y pixels (global NHWC), 9 taps x 8
// ic-chunks of 32. D: row=oc=(lane>>4)*4+reg, col=px=lane&15.
// ---------------------------------------------------------------------------
__global__ __launch_bounds__(256) void conv_mfma(const unsigned short* __restrict__ yws,
                                                 const unsigned short* __restrict__ wt,
                                                 float* __restrict__ out) {
    __shared__ char s_wt[16384];          // 32 oc * 512B (256 ic bf16), swizzled

    int b0 = blockIdx.x;
    int bid = (b0 & 7) * 112 + (b0 >> 3);            // XCD-chunked swizzle (896 = 8*112)
    int n = bid / 28, h0 = (bid - n * 28) * 2;

    int t = threadIdx.x, lane = t & 63, wv = t >> 6;
    int l15 = lane & 15, koct = lane >> 4;
    int pt0 = wv * 2, pt1 = (wv < 3) ? wv * 2 + 1 : 6;   // wave3: dup tile 6

    int px0 = pt0 * 16 + l15, px1 = pt1 * 16 + l15;
    int r0 = px0 >= 56, w0 = px0 - 56 * r0;
    int r1 = px1 >= 56, w1 = px1 - 56 * r1;

    const char* ybase = (const char*)yws + (size_t)n * YIMG * 2;
    int po0 = ((h0 + r0) * YP + w0) * 512 + koct * 16;   // bytes within image
    int po1 = ((h0 + r1) * YP + w1) * 512 + koct * 16;

    f32x4 acc[2][2] = {};                 // [oc-tile][px-tile]
    int swz = (l15 & 7) << 4;

    for (int tap = 0; tap < 9; ++tap) {
        __syncthreads();
        #pragma unroll
        for (int i = 0; i < 4; ++i) {     // stage 16KB: 1024 16B-chunks
            int id = i * 256 + t;
            int oc = id >> 5, icb = id & 31;
            uint4 v = *(const uint4*)(wt + tap * 8192 + oc * 256 + icb * 8);
            *(uint4*)(s_wt + oc * 512 + ((icb * 16) ^ ((oc & 7) << 4))) = v;
        }
        __syncthreads();

        int kh = tap / 3, kw = tap - kh * 3;
        int toff = (kh * YP + kw) * 512;

        #pragma unroll
        for (int c = 0; c < 8; ++c) {
            int aoff = (c * 64 + koct * 16) ^ swz;
            short8 a0 = *(short8*)(s_wt + l15 * 512 + aoff);
            short8 a1 = *(short8*)(s_wt + 8192 + l15 * 512 + aoff);
            short8 b0v = *(const short8*)(ybase + po0 + toff + c * 64);
            short8 b1v = *(const short8*)(ybase + po1 + toff + c * 64);
            acc[0][0] = __builtin_amdgcn_mfma_f32_16x16x32_bf16(a0, b0v, acc[0][0], 0, 0, 0);
            acc[1][0] = __builtin_amdgcn_mfma_f32_16x16x32_bf16(a1, b0v, acc[1][0], 0, 0, 0);
            acc[0][1] = __builtin_amdgcn_mfma_f32_16x16x32_bf16(a0, b1v, acc[0][1], 0, 0, 0);
            acc[1][1] = __builtin_amdgcn_mfma_f32_16x16x32_bf16(a1, b1v, acc[1][1], 0, 0, 0);
        }
    }

    float* ob = out + (size_t)n * CHW + (size_t)C_IN * PLANE + (size_t)h0 * HWDIM;
    #pragma unroll
    for (int oct = 0; oct < 2; ++oct) {
        #pragma unroll
        for (int p = 0; p < 2; ++p) {
            if (p == 1 && wv == 3) continue;          // dup tile, don't store
            int rr = p ? r1 : r0, wc = p ? w1 : w0;
            #pragma unroll
            for (int j = 0; j < 4; ++j) {
                int oc = oct * 16 + koct * 4 + j;
                ob[(size_t)oc * PLANE + rr * HWDIM + wc] = acc[oct][p][j];
            }
        }
    }
}

// ---------------------------------------------------------------------------
// Fallback fp32 kernel (ws too small) — round-0 kernel with the OOB-row BN
// bug fixed (padded rows contribute 0, not relu(shift)).
// ---------------------------------------------------------------------------
__global__ __launch_bounds__(256) void fused_bn_relu_conv(
    const float* __restrict__ xin, const float* __restrict__ bnw,
    const float* __restrict__ bnb, const float* __restrict__ rmean,
    const float* __restrict__ rvar, const float* __restrict__ cw,
    float* __restrict__ out)
{
    __shared__ float s_scale[C_IN];
    __shared__ float s_shift[C_IN];
    __shared__ float s_y[3][32][60];

    const int h = blockIdx.x, n = blockIdx.y, t = threadIdx.x;
    {
        float sc = bnw[t] * rsqrtf(rvar[t] + EPSV);
        s_scale[t] = sc;
        s_shift[t] = bnb[t] - rmean[t] * sc;
    }
    const int oc = t >> 3;
    const int w0 = (t & 7) * 7;
    float acc[7];
    #pragma unroll
    for (int j = 0; j < 7; ++j) acc[j] = 0.f;
    const size_t nbase = (size_t)n * CHW;

    for (int cb = 0; cb < 8; ++cb) {
        __syncthreads();
        for (int idx = t; idx < 3 * 32 * 15; idx += 256) {
            int r = idx / 480, rem = idx - r * 480;
            int ic = rem / 15, s = rem - ic * 15;
            int icg = (cb << 5) + ic, hr = h - 1 + r;
            if (s < 14) {
                float4 x = make_float4(0.f, 0.f, 0.f, 0.f);
                bool inb = (unsigned)hr < HWDIM;
                if (inb) {
                    const float* gp = xin + nbase + (size_t)icg * PLANE + hr * HWDIM + (s << 2);
                    x = *reinterpret_cast<const float4*>(gp);
                    if (r == 1) {
                        float* op = out + nbase + (size_t)icg * PLANE + h * HWDIM + (s << 2);
                        *reinterpret_cast<float4*>(op) = x;
                    }
                }
                float sc = s_scale[icg], sh = s_shift[icg];
                int e = (s << 2) + 1;
                s_y[r][ic][e + 0] = inb ? fmaxf(fmaf(x.x, sc, sh), 0.f) : 0.f;
                s_y[r][ic][e + 1] = inb ? fmaxf(fmaf(x.y, sc, sh), 0.f) : 0.f;
                s_y[r][ic][e + 2] = inb ? fmaxf(fmaf(x.z, sc, sh), 0.f) : 0.f;
                s_y[r][ic][e + 3] = inb ? fmaxf(fmaf(x.w, sc, sh), 0.f) : 0.f;
            } else {
                s_y[r][ic][0] = 0.f; s_y[r][ic][57] = 0.f;
            }
        }
        __syncthreads();
        const float* wbase = cw + ((size_t)oc * C_IN + (cb << 5)) * 9;
        #pragma unroll 2
        for (int ic = 0; ic < 32; ++ic) {
            const float* wp = wbase + ic * 9;
            float wk[9];
            #pragma unroll
            for (int k = 0; k < 9; ++k) wk[k] = wp[k];
            #pragma unroll
            for (int r = 0; r < 3; ++r) {
                float yy[9];
                #pragma unroll
                for (int j = 0; j < 9; ++j) yy[j] = s_y[r][ic][w0 + j];
                #pragma unroll
                for (int kw = 0; kw < 3; ++kw) {
                    float wv2 = wk[r * 3 + kw];
                    #pragma unroll
                    for (int j = 0; j < 7; ++j)
                        acc[j] = fmaf(yy[j + kw], wv2, acc[j]);
                }
            }
        }
    }
    float* op = out + nbase + (size_t)(C_IN + oc) * PLANE + h * HWDIM + w0;
    #pragma unroll
    for (int j = 0; j < 7; ++j) op[j] = acc[j];
}

extern "C" void kernel_launch(void* const* d_in, const int* in_sizes, int n_in,
                              void* d_out, int out_size, void* d_ws, size_t ws_size,
                              hipStream_t stream) {
    const float* xin = (const float*)d_in[0];
    const float* bnw = (const float*)d_in[1];
    const float* bnb = (const float*)d_in[2];
    const float* rm  = (const float*)d_in[3];
    const float* rv  = (const float*)d_in[4];
    const float* cwt = (const float*)d_in[5];
    float* out = (float*)d_out;

    if (ws_size < WS_NEED) {   // safety: fp32 fallback
        dim3 grid(HWDIM, N_IMG);
        fused_bn_relu_conv<<<grid, 256, 0, stream>>>(xin, bnw, bnb, rm, rv, cwt, out);
        return;
    }

    unsigned short* yws = (unsigned short*)d_ws;
    unsigned short* wtb = yws + YWS_ELEMS;

    prep_kernel<<<1200, 256, 0, stream>>>(cwt, yws, wtb);
    bn_relu_pack<<<dim3(HWDIM, N_IMG), 256, 0, stream>>>(xin, bnw, bnb, rm, rv, out, yws);
    conv_mfma<<<896, 256, 0, stream>>>(yws, wtb, out);
}

// Round 4
// 327.125 us; speedup vs baseline: 1.5398x; 1.0083x over previous
//
#include <hip/hip_runtime.h>

typedef short short8 __attribute__((ext_vector_type(8)));
typedef float f32x4 __attribute__((ext_vector_type(4)));

#define N_IMG 32
#define C_IN  256
#define C_OUT 32
#define HWDIM 56
#define C_TOT 288
#define EPSV  1e-5f
#define PLANE (HWDIM * HWDIM)      // 3136
#define CHW   (C_TOT * PLANE)      // 903168

// padded bf16 NHWC y workspace: [n][58][58][256]
#define YP    58
#define YROW  (YP * C_IN)          // 14848 elems per padded row
#define YIMG  (YP * YROW)          // 861184 elems per image
#define YWS_ELEMS ((size_t)N_IMG * YIMG)
#define WT_ELEMS  (9 * C_OUT * C_IN)          // 73728
#define WS_NEED   (YWS_ELEMS * 2 + (size_t)WT_ELEMS * 2)

static __device__ __forceinline__ unsigned short f2bf(float f) {
    union { float f; unsigned u; } v; v.f = f;
    unsigned r = (v.u + 0x7FFFu + ((v.u >> 16) & 1u)) >> 16;   // RNE
    return (unsigned short)r;
}

// ---------------------------------------------------------------------------
// prep: (a) zero padded borders of yws  (b) convert conv weights to bf16 in a
// PRE-SWIZZLED layout so conv's LDS staging is a LINEAR copy whose image
// matches the XOR-swizzled A-read pattern:
//   16B-granule j of tap-plane:  oc = j>>5, icb = (j&31) ^ (oc&7)
// ---------------------------------------------------------------------------
__global__ __launch_bounds__(256) void prep_kernel(const float* __restrict__ cw,
                                                   unsigned short* __restrict__ yws,
                                                   unsigned short* __restrict__ wt) {
    int b = blockIdx.x, t = threadIdx.x;
    if (b < 912) {
        int gid = b * 256 + t;            // 32 img * 228 border px * 32 chunks
        int px = gid >> 5, ch = gid & 31;
        int n = px / 228, r = px % 228;
        int hh, ww;
        if (r < 58)       { hh = 0;        ww = r;       }
        else if (r < 116) { hh = 57;       ww = r - 58;  }
        else if (r < 172) { hh = r - 115;  ww = 0;       }
        else              { hh = r - 171;  ww = 57;      }
        uint4 z = {0u, 0u, 0u, 0u};
        *(uint4*)((char*)yws + ((size_t)n * YIMG + (size_t)hh * YROW + (size_t)ww * C_IN) * 2 + ch * 16) = z;
    } else {
        int id  = (b - 912) * 256 + t;    // 0..73727
        int tap = id >> 13;
        int pos = id & 8191;
        int g   = pos >> 3, r = pos & 7;
        int oc  = g >> 5;
        int icb = (g & 31) ^ (oc & 7);
        int ic  = icb * 8 + r;
        wt[id] = f2bf(cw[(oc * C_IN + ic) * 9 + tap]);
    }
}

// ---------------------------------------------------------------------------
// k1: passthrough copy (fp32 NCHW) + BN+ReLU -> bf16 NHWC-padded workspace.
// 1024 threads per (h, n). LDS layout [c][w] stride 66 shorts:
//   phase1 writes: consecutive-c lanes pairs -> conflict-free b32 writes
//   phase2 reads : consecutive-c lanes, b32 (2 px)  -> conflict-free;
//                  global ushort stores 128B-contiguous per wave.
// ---------------------------------------------------------------------------
__global__ __launch_bounds__(1024) void bn_relu_pack(const float* __restrict__ xin,
                                                     const float* __restrict__ bnw,
                                                     const float* __restrict__ bnb,
                                                     const float* __restrict__ rmean,
                                                     const float* __restrict__ rvar,
                                                     float* __restrict__ out,
                                                     unsigned short* __restrict__ yws) {
    __shared__ float s_scale[C_IN], s_shift[C_IN];
    __shared__ unsigned short s_yc[C_IN * 66];   // [c][w], stride 66 (33792 B)

    int h = blockIdx.x, n = blockIdx.y, t = threadIdx.x;
    if (t < C_IN) {
        float sc = bnw[t] * rsqrtf(rvar[t] + EPSV);
        s_scale[t] = sc;
        s_shift[t] = bnb[t] - rmean[t] * sc;
    }
    __syncthreads();

    const size_t nb = (size_t)n * CHW + (size_t)h * HWDIM;
    #pragma unroll
    for (int i = 0; i < 4; ++i) {
        int id = i * 1024 + t;            // 3584 tasks = 256 c * 14 w-quads
        if (id < 3584) {
            int c = id / 14, wq = id - c * 14;
            const float* gp = xin + nb + (size_t)c * PLANE + wq * 4;
            float4 x = *(const float4*)gp;
            *(float4*)(out + nb + (size_t)c * PLANE + wq * 4) = x;   // fused passthrough
            float sc = s_scale[c], sh = s_shift[c];
            unsigned p0 = (unsigned)f2bf(fmaxf(fmaf(x.x, sc, sh), 0.f))
                        | ((unsigned)f2bf(fmaxf(fmaf(x.y, sc, sh), 0.f)) << 16);
            unsigned p1 = (unsigned)f2bf(fmaxf(fmaf(x.z, sc, sh), 0.f))
                        | ((unsigned)f2bf(fmaxf(fmaf(x.w, sc, sh), 0.f)) << 16);
            *(unsigned*)(&s_yc[c * 66 + 4 * wq])     = p0;
            *(unsigned*)(&s_yc[c * 66 + 4 * wq + 2]) = p1;
        }
    }
    __syncthreads();

    unsigned short* ybase = yws + (size_t)n * YIMG + (size_t)(h + 1) * YROW + C_IN; // col 1
    #pragma unroll
    for (int i = 0; i < 7; ++i) {
        int id = i * 1024 + t;            // 7168 = 256 c * 28 px-pairs
        int c = id & 255, pq = id >> 8;   // pq 0..27
        unsigned v = *(const unsigned*)(&s_yc[c * 66 + 2 * pq]);
        ybase[(size_t)(2 * pq)     * C_IN + c] = (unsigned short)(v & 0xFFFFu);
        ybase[(size_t)(2 * pq + 1) * C_IN + c] = (unsigned short)(v >> 16);
    }
}

// ---------------------------------------------------------------------------
// k2: implicit-GEMM conv via MFMA, software-pipelined:
//  - A (weights) double-buffered in LDS across taps (issue-early/write-late)
//  - all 16 B-fragments batch-loaded per tap before the 32 MFMAs
// Block = 256 thr (4 waves), 2 output rows. D: row=oc=(lane>>4)*4+reg,
// col=px=lane&15 (verified round 2).
// ---------------------------------------------------------------------------
__global__ __launch_bounds__(256) void conv_mfma(const unsigned short* __restrict__ yws,
                                                 const unsigned short* __restrict__ wt,
                                                 float* __restrict__ out) {
    __shared__ unsigned short s_wt[2][8192];      // 2 x 16KB, double-buffered

    int b0 = blockIdx.x;
    int bid = (b0 & 7) * 112 + (b0 >> 3);         // XCD-chunked swizzle (896 = 8*112)
    int n = bid / 28, h0 = (bid - n * 28) * 2;

    int t = threadIdx.x, lane = t & 63, wv = t >> 6;
    int l15 = lane & 15, koct = lane >> 4;
    int pt0 = wv * 2, pt1 = (wv < 3) ? wv * 2 + 1 : 6;   // wave3: dup tile 6

    int px0 = pt0 * 16 + l15, px1 = pt1 * 16 + l15;
    int r0 = px0 >= 56, w0 = px0 - 56 * r0;
    int r1 = px1 >= 56, w1 = px1 - 56 * r1;

    const char* ybase = (const char*)yws + (size_t)n * YIMG * 2;
    int po0 = ((h0 + r0) * YP + w0) * 512 + koct * 16;
    int po1 = ((h0 + r1) * YP + w1) * 512 + koct * 16;
    int swz = (l15 & 7) << 4;

    // stage tap 0 into buffer 0 (linear copy; wt is pre-swizzled)
    {
        uint4 st0, st1, st2, st3;
        st0 = *(const uint4*)(wt + (0 * 256 + t) * 8);
        st1 = *(const uint4*)(wt + (1 * 256 + t) * 8);
        st2 = *(const uint4*)(wt + (2 * 256 + t) * 8);
        st3 = *(const uint4*)(wt + (3 * 256 + t) * 8);
        *(uint4*)((char*)s_wt[0] + (0 * 256 + t) * 16) = st0;
        *(uint4*)((char*)s_wt[0] + (1 * 256 + t) * 16) = st1;
        *(uint4*)((char*)s_wt[0] + (2 * 256 + t) * 16) = st2;
        *(uint4*)((char*)s_wt[0] + (3 * 256 + t) * 16) = st3;
    }
    __syncthreads();

    f32x4 acc00 = {}, acc01 = {}, acc10 = {}, acc11 = {};

    #pragma unroll
    for (int tap = 0; tap < 9; ++tap) {
        const int cur = tap & 1;

        // issue next tap's A loads early (land after this tap's MFMAs)
        uint4 nt0, nt1, nt2, nt3;
        if (tap < 8) {
            const unsigned short* g = wt + (size_t)(tap + 1) * 8192;
            nt0 = *(const uint4*)(g + (0 * 256 + t) * 8);
            nt1 = *(const uint4*)(g + (1 * 256 + t) * 8);
            nt2 = *(const uint4*)(g + (2 * 256 + t) * 8);
            nt3 = *(const uint4*)(g + (3 * 256 + t) * 8);
        }

        int kh = tap / 3, kw = tap - kh * 3;
        const char* yb0 = ybase + po0 + (kh * YP + kw) * 512;
        const char* yb1 = ybase + po1 + (kh * YP + kw) * 512;

        // batch-load all B fragments for this tap
        short8 B0[8], B1[8];
        #pragma unroll
        for (int c = 0; c < 8; ++c) {
            B0[c] = *(const short8*)(yb0 + c * 64);
            B1[c] = *(const short8*)(yb1 + c * 64);
        }

        const char* sw = (const char*)s_wt[cur];
        #pragma unroll
        for (int c = 0; c < 8; ++c) {
            int aoff = (c * 64 + koct * 16) ^ swz;
            short8 a0 = *(const short8*)(sw + l15 * 512 + aoff);
            short8 a1 = *(const short8*)(sw + 8192 + l15 * 512 + aoff);
            acc00 = __builtin_amdgcn_mfma_f32_16x16x32_bf16(a0, B0[c], acc00, 0, 0, 0);
            acc10 = __builtin_amdgcn_mfma_f32_16x16x32_bf16(a1, B0[c], acc10, 0, 0, 0);
            acc01 = __builtin_amdgcn_mfma_f32_16x16x32_bf16(a0, B1[c], acc01, 0, 0, 0);
            acc11 = __builtin_amdgcn_mfma_f32_16x16x32_bf16(a1, B1[c], acc11, 0, 0, 0);
        }

        // write next tap's A into the other buffer (overlaps with MFMA reads of cur)
        if (tap < 8) {
            char* dw = (char*)s_wt[cur ^ 1];
            *(uint4*)(dw + (0 * 256 + t) * 16) = nt0;
            *(uint4*)(dw + (1 * 256 + t) * 16) = nt1;
            *(uint4*)(dw + (2 * 256 + t) * 16) = nt2;
            *(uint4*)(dw + (3 * 256 + t) * 16) = nt3;
        }
        __syncthreads();
    }

    float* ob = out + (size_t)n * CHW + (size_t)C_IN * PLANE + (size_t)h0 * HWDIM;
    {
        #pragma unroll
        for (int j = 0; j < 4; ++j) {
            int oc0 = koct * 4 + j;
            ob[(size_t)oc0 * PLANE + r0 * HWDIM + w0]        = acc00[j];
            ob[(size_t)(16 + oc0) * PLANE + r0 * HWDIM + w0] = acc10[j];
            if (wv < 3) {
                ob[(size_t)oc0 * PLANE + r1 * HWDIM + w1]        = acc01[j];
                ob[(size_t)(16 + oc0) * PLANE + r1 * HWDIM + w1] = acc11[j];
            }
        }
    }
}

extern "C" void kernel_launch(void* const* d_in, const int* in_sizes, int n_in,
                              void* d_out, int out_size, void* d_ws, size_t ws_size,
                              hipStream_t stream) {
    const float* xin = (const float*)d_in[0];
    const float* bnw = (const float*)d_in[1];
    const float* bnb = (const float*)d_in[2];
    const float* rm  = (const float*)d_in[3];
    const float* rv  = (const float*)d_in[4];
    const float* cwt = (const float*)d_in[5];
    float* out = (float*)d_out;

    unsigned short* yws = (unsigned short*)d_ws;
    unsigned short* wtb = yws + YWS_ELEMS;

    prep_kernel<<<1200, 256, 0, stream>>>(cwt, yws, wtb);
    bn_relu_pack<<<dim3(HWDIM, N_IMG), 1024, 0, stream>>>(xin, bnw, bnb, rm, rv, out, yws);
    conv_mfma<<<896, 256, 0, stream>>>(yws, wtb, out);
}